// Round 1
// baseline (2643.229 us; speedup 1.0000x reference)
//
#include <hip/hip_runtime.h>
#include <cstdint>

#define MDIM 24000   // N*T rows
#define DDIM 1024
#define CDIM 20
#define TDIM 750
#define NBATCH 32
#define KSEL 657     // T - T//S
#define MASKV -100.0f
#define OMEGAF 0.6f

// d_out element offsets (return order: x_r, cls_x_r, cls_x_ra, x_f, cls_x_f, cls_x_fa, tcam)
#define OFF_XR     0L
#define OFF_CLSX_R 24576000L
#define OFF_CLSRA  25056000L
#define OFF_XF     25536000L
#define OFF_CLSX_F 50112000L
#define OFF_CLSFA  50592000L
#define OFF_TCAM   51072000L

// C[m][n] = relu( sum_k A[m][k] * W[n][k] + bias[n] ),  M=24000, N=1024, K=1024
// 128x128 tile, BK=16, 256 threads, 8x8 per thread, k-major LDS.
__global__ __launch_bounds__(256)
void gemm_relu_f32(const float* __restrict__ A, int lda,
                   const float* __restrict__ W,
                   const float* __restrict__ bias,
                   float* __restrict__ Cout) {
    __shared__ float As[16][140];
    __shared__ float Bs[16][140];
    const int tid = threadIdx.x;
    const int tx = tid & 15, ty = tid >> 4;
    const long bm = (long)blockIdx.x * 128;
    const int bn = blockIdx.y * 128;

    float acc[8][8];
#pragma unroll
    for (int i = 0; i < 8; ++i)
#pragma unroll
        for (int j = 0; j < 8; ++j) acc[i][j] = 0.f;

    for (int k0 = 0; k0 < DDIM; k0 += 16) {
        __syncthreads();
#pragma unroll
        for (int h = 0; h < 2; ++h) {
            const int c = tid + h * 256;     // 0..511
            const int row = c >> 2;          // 0..127
            const int kc = (c & 3) << 2;     // 0,4,8,12
            long ar = bm + row; if (ar > MDIM - 1) ar = MDIM - 1;
            const float4 va = *reinterpret_cast<const float4*>(&A[ar * lda + k0 + kc]);
            As[kc + 0][row] = va.x; As[kc + 1][row] = va.y;
            As[kc + 2][row] = va.z; As[kc + 3][row] = va.w;
            const float4 vb = *reinterpret_cast<const float4*>(&W[(long)(bn + row) * DDIM + k0 + kc]);
            Bs[kc + 0][row] = vb.x; Bs[kc + 1][row] = vb.y;
            Bs[kc + 2][row] = vb.z; Bs[kc + 3][row] = vb.w;
        }
        __syncthreads();
#pragma unroll
        for (int kk = 0; kk < 16; ++kk) {
            float a[8], b[8];
            *(float4*)&a[0] = *(const float4*)&As[kk][ty * 8];
            *(float4*)&a[4] = *(const float4*)&As[kk][ty * 8 + 4];
            *(float4*)&b[0] = *(const float4*)&Bs[kk][tx * 8];
            *(float4*)&b[4] = *(const float4*)&Bs[kk][tx * 8 + 4];
#pragma unroll
            for (int i = 0; i < 8; ++i)
#pragma unroll
                for (int j = 0; j < 8; ++j)
                    acc[i][j] = fmaf(a[i], b[j], acc[i][j]);
        }
    }

    float bv[8];
#pragma unroll
    for (int j = 0; j < 8; ++j) bv[j] = bias[bn + tx * 8 + j];
#pragma unroll
    for (int i = 0; i < 8; ++i) {
        const long row = bm + ty * 8 + i;
        if (row < MDIM) {
            float o[8];
#pragma unroll
            for (int j = 0; j < 8; ++j) o[j] = fmaxf(acc[i][j] + bv[j], 0.f);
            *(float4*)&Cout[row * DDIM + bn + tx * 8]     = *(float4*)&o[0];
            *(float4*)&Cout[row * DDIM + bn + tx * 8 + 4] = *(float4*)&o[4];
        }
    }
}

// cls_x[m][c] = H[m][:] . Wc[c][:] + bc[c]   (c<20)  -> clsx
// at[m][c]    = H[m][:] . Wa[c][:] + ba[c]   (c<20)  -> atout
// N-dim padded to 48 (cols 0..19 cls, 20..39 at, 40..47 dead).
__global__ __launch_bounds__(256)
void cls_gemm_f32(const float* __restrict__ H,
                  const float* __restrict__ Wc, const float* __restrict__ bc,
                  const float* __restrict__ Wa, const float* __restrict__ ba,
                  float* __restrict__ clsx, float* __restrict__ atout) {
    __shared__ float As[16][140];
    __shared__ float Bs[16][48];
    const int tid = threadIdx.x;
    const int tx = tid & 15, ty = tid >> 4;
    const long bm = (long)blockIdx.x * 128;

    float acc[8][3];
#pragma unroll
    for (int i = 0; i < 8; ++i)
#pragma unroll
        for (int j = 0; j < 3; ++j) acc[i][j] = 0.f;

    for (int k0 = 0; k0 < DDIM; k0 += 16) {
        __syncthreads();
#pragma unroll
        for (int h = 0; h < 2; ++h) {
            const int c = tid + h * 256;
            const int row = c >> 2;
            const int kc = (c & 3) << 2;
            long ar = bm + row; if (ar > MDIM - 1) ar = MDIM - 1;
            const float4 va = *reinterpret_cast<const float4*>(&H[ar * DDIM + k0 + kc]);
            As[kc + 0][row] = va.x; As[kc + 1][row] = va.y;
            As[kc + 2][row] = va.z; As[kc + 3][row] = va.w;
        }
        if (tid < 192) {
            const int n = tid >> 2;
            const int kc = (tid & 3) << 2;
            float4 w = make_float4(0.f, 0.f, 0.f, 0.f);
            if (n < 20)      w = *reinterpret_cast<const float4*>(&Wc[(long)n * DDIM + k0 + kc]);
            else if (n < 40) w = *reinterpret_cast<const float4*>(&Wa[(long)(n - 20) * DDIM + k0 + kc]);
            Bs[kc + 0][n] = w.x; Bs[kc + 1][n] = w.y;
            Bs[kc + 2][n] = w.z; Bs[kc + 3][n] = w.w;
        }
        __syncthreads();
#pragma unroll
        for (int kk = 0; kk < 16; ++kk) {
            float a[8];
            *(float4*)&a[0] = *(const float4*)&As[kk][ty * 8];
            *(float4*)&a[4] = *(const float4*)&As[kk][ty * 8 + 4];
            const float b0 = Bs[kk][tx];
            const float b1 = Bs[kk][tx + 16];
            const float b2 = Bs[kk][tx + 32];
#pragma unroll
            for (int i = 0; i < 8; ++i) {
                acc[i][0] = fmaf(a[i], b0, acc[i][0]);
                acc[i][1] = fmaf(a[i], b1, acc[i][1]);
                acc[i][2] = fmaf(a[i], b2, acc[i][2]);
            }
        }
    }

#pragma unroll
    for (int j = 0; j < 3; ++j) {
        const int col = tx + 16 * j;
        const bool isC = (col < 20);
        const bool isA = (col >= 20) && (col < 40);
        const float bvv = isC ? bc[col] : (isA ? ba[col - 20] : 0.f);
#pragma unroll
        for (int i = 0; i < 8; ++i) {
            const long row = bm + ty * 8 + i;
            if (row < MDIM) {
                const float v = acc[i][j] + bvv;
                if (isC)      clsx[row * CDIM + col] = v;
                else if (isA) atout[row * CDIM + col - 20] = v;
            }
        }
    }
}

// One block per (stream, n, c): bitonic-sort the 750 values (padded to 1024
// with +inf) and emit the K-th smallest (index KSEL-1).
__global__ __launch_bounds__(512)
void select_kth(const float* __restrict__ clsx_r, const float* __restrict__ clsx_f,
                float* __restrict__ kth) {
    __shared__ float s[1024];
    const int b = blockIdx.x;            // 0..1279
    const int z = b / 640;
    const int rem = b - z * 640;
    const int n = rem / CDIM;
    const int c = rem - n * CDIM;
    const float* src = (z == 0) ? clsx_r : clsx_f;
    const int tid = threadIdx.x;

    for (int i = tid; i < 1024; i += 512)
        s[i] = (i < TDIM) ? src[((long)n * TDIM + i) * CDIM + c] : 3.402823466e38f;
    __syncthreads();

    for (int k = 2; k <= 1024; k <<= 1) {
        for (int j = k >> 1; j > 0; j >>= 1) {
            for (int i = tid; i < 1024; i += 512) {
                const int ixj = i ^ j;
                if (ixj > i) {
                    const bool up = ((i & k) == 0);
                    const float x = s[i], y = s[ixj];
                    if ((x > y) == up) { s[i] = y; s[ixj] = x; }
                }
            }
            __syncthreads();
        }
    }
    if (tid == 0) kth[b] = s[KSEL - 1];
}

// Reads cls_x from d_out and the stashed cls_at (stored in the ra/fa slots),
// applies the mask in place, writes tcam.
__global__ __launch_bounds__(256)
void final_mask(float* __restrict__ out, const float* __restrict__ kth,
                const float* __restrict__ mul_r, const float* __restrict__ mul_f) {
    const int idx = blockIdx.x * 256 + threadIdx.x;
    if (idx >= NBATCH * TDIM * CDIM) return;
    const int m = idx / CDIM;
    const int c = idx - m * CDIM;
    const int n = m / TDIM;
    const float xr  = out[OFF_CLSX_R + idx];
    const float xf  = out[OFF_CLSX_F + idx];
    const float atr = out[OFF_CLSRA + idx];
    const float atf = out[OFF_CLSFA + idx];
    const float kr = kth[n * CDIM + c];
    const float kf = kth[640 + n * CDIM + c];
    out[OFF_CLSRA + idx] = (xr > kr) ? MASKV : atr;
    out[OFF_CLSFA + idx] = (xf > kf) ? MASKV : atf;
    out[OFF_TCAM + idx]  = (xr + OMEGAF * atr) * mul_r[c] + (xf + OMEGAF * atf) * mul_f[c];
}

extern "C" void kernel_launch(void* const* d_in, const int* in_sizes, int n_in,
                              void* d_out, int out_size, void* d_ws, size_t ws_size,
                              hipStream_t stream) {
    const float* inp    = (const float*)d_in[0];
    const float* Wfc_r  = (const float*)d_in[1];
    const float* bfc_r  = (const float*)d_in[2];
    const float* Wfc1_r = (const float*)d_in[3];
    const float* bfc1_r = (const float*)d_in[4];
    const float* Wfc_f  = (const float*)d_in[5];
    const float* bfc_f  = (const float*)d_in[6];
    const float* Wfc1_f = (const float*)d_in[7];
    const float* bfc1_f = (const float*)d_in[8];
    const float* Wcls_r = (const float*)d_in[9];
    const float* bcls_r = (const float*)d_in[10];
    const float* Wcls_f = (const float*)d_in[11];
    const float* bcls_f = (const float*)d_in[12];
    const float* Wra    = (const float*)d_in[13];
    const float* bra    = (const float*)d_in[14];
    const float* Wfa    = (const float*)d_in[15];
    const float* bfa    = (const float*)d_in[16];
    const float* mul_r  = (const float*)d_in[17];
    const float* mul_f  = (const float*)d_in[18];

    float* out = (float*)d_out;
    float* H1  = (float*)d_ws;               // 24000*1024 f32 = 98.3 MB
    float* kth = H1 + (long)MDIM * DDIM;     // 1280 f32

    dim3 blk(256);
    dim3 g1(188, 8);

    // RGB stream
    gemm_relu_f32<<<g1, blk, 0, stream>>>(inp,        2 * DDIM, Wfc_r,  bfc_r,  H1);
    gemm_relu_f32<<<g1, blk, 0, stream>>>(H1,         DDIM,     Wfc1_r, bfc1_r, out + OFF_XR);
    cls_gemm_f32<<<dim3(188), blk, 0, stream>>>(out + OFF_XR, Wcls_r, bcls_r, Wra, bra,
                                                out + OFF_CLSX_R, out + OFF_CLSRA);
    // Flow stream
    gemm_relu_f32<<<g1, blk, 0, stream>>>(inp + DDIM, 2 * DDIM, Wfc_f,  bfc_f,  H1);
    gemm_relu_f32<<<g1, blk, 0, stream>>>(H1,         DDIM,     Wfc1_f, bfc1_f, out + OFF_XF);
    cls_gemm_f32<<<dim3(188), blk, 0, stream>>>(out + OFF_XF, Wcls_f, bcls_f, Wfa, bfa,
                                                out + OFF_CLSX_F, out + OFF_CLSFA);

    select_kth<<<dim3(1280), dim3(512), 0, stream>>>(out + OFF_CLSX_R, out + OFF_CLSX_F, kth);
    final_mask<<<dim3((NBATCH * TDIM * CDIM + 255) / 256), blk, 0, stream>>>(out, kth, mul_r, mul_f);
}

// Round 2
// 1247.972 us; speedup vs baseline: 2.1180x; 2.1180x over previous
//
#include <hip/hip_runtime.h>
#include <cstdint>

typedef _Float16 f16x8 __attribute__((ext_vector_type(8)));
typedef float f32x4 __attribute__((ext_vector_type(4)));

#define MDIM 24000   // N*T rows
#define DDIM 1024
#define CDIM 20
#define TDIM 750
#define NBATCH 32
#define KSEL 657
#define MASKV -100.0f
#define OMEGAF 0.6f
#define SPLIT_SCALE 2048.0f
#define SPLIT_INV   4.8828125e-4f   // 2^-11 exact

// d_out element offsets (x_r, cls_x_r, cls_x_ra, x_f, cls_x_f, cls_x_fa, tcam)
#define OFF_XR     0L
#define OFF_CLSX_R 24576000L
#define OFF_CLSRA  25056000L
#define OFF_XF     25536000L
#define OFF_CLSX_F 50112000L
#define OFF_CLSFA  50592000L
#define OFF_TCAM   51072000L

#define GLOAD16(g, l) __builtin_amdgcn_global_load_lds( \
    (const __attribute__((address_space(1))) void*)(g), \
    (__attribute__((address_space(3))) void*)(l), 16, 0, 0)

// Split fp32 -> (hi f16, lo f16*2^11). dst flat index = v*8 (dense rows of 1024).
__global__ __launch_bounds__(256)
void split_f16(const float* __restrict__ src, long srcStride, long nrows,
               _Float16* __restrict__ D0, _Float16* __restrict__ D1) {
    const long nvec = nrows * 128;
    for (long v = (long)blockIdx.x * 256 + threadIdx.x; v < nvec; v += (long)gridDim.x * 256) {
        const long row = v >> 7;
        const int c8 = (int)(v & 127) << 3;
        const float4 x0 = *reinterpret_cast<const float4*>(&src[row * srcStride + c8]);
        const float4 x1 = *reinterpret_cast<const float4*>(&src[row * srcStride + c8 + 4]);
        float xs[8] = {x0.x, x0.y, x0.z, x0.w, x1.x, x1.y, x1.z, x1.w};
        f16x8 h0, h1;
#pragma unroll
        for (int j = 0; j < 8; ++j) {
            const _Float16 a = (_Float16)xs[j];
            h0[j] = a;
            h1[j] = (_Float16)((xs[j] - (float)a) * SPLIT_SCALE);
        }
        *reinterpret_cast<f16x8*>(&D0[v << 3]) = h0;
        *reinterpret_cast<f16x8*>(&D1[v << 3]) = h1;
    }
}

// C = relu(A.W^T + bias) via split-f16 MFMA, K' = 3072:
//   panels (A0,B1),(A1,B0) -> acc *= 2^-11 (exact) -> panel (A0,B0).
// MODE 0: write split H0,H1 (f16).  MODE 1: write fp32 to outF.
// 128x128 tile, BK=64, 4 waves (2x2), 4x4 frags of 16x16x32 f16 per wave.
template<int MODE>
__global__ __launch_bounds__(256)
void gemm_split_f16(const _Float16* __restrict__ A0, const _Float16* __restrict__ A1,
                    const _Float16* __restrict__ B0, const _Float16* __restrict__ B1,
                    const float* __restrict__ bias,
                    float* __restrict__ outF,
                    _Float16* __restrict__ H0, _Float16* __restrict__ H1) {
    __shared__ _Float16 As[128][64];
    __shared__ _Float16 Bs[128][64];
    const int t = threadIdx.x;
    const int lane = t & 63;
    const int wave = t >> 6;
    const int wr = wave >> 1, wc = wave & 1;
    const int lr = lane & 15, lk = lane >> 4;
    const long bm = (long)blockIdx.x * 128;
    const int bn = blockIdx.y * 128;

    f32x4 acc[4][4];
#pragma unroll
    for (int mi = 0; mi < 4; ++mi)
#pragma unroll
        for (int ni = 0; ni < 4; ++ni)
            acc[mi][ni] = (f32x4){0.f, 0.f, 0.f, 0.f};

    const int srow = t >> 3;         // 0..31
    const int scol = (t & 7) << 3;   // 0,8,..,56

    for (int step = 0; step < 48; ++step) {
        const int p = step >> 4;
        const int k0 = (step & 15) << 6;
        const _Float16* __restrict__ Ab = (p == 1) ? A1 : A0;
        const _Float16* __restrict__ Bb = (p == 0) ? B1 : B0;
        if (step == 32) {   // exact 2^-11 rescale of the two lo-panels
#pragma unroll
            for (int mi = 0; mi < 4; ++mi)
#pragma unroll
                for (int ni = 0; ni < 4; ++ni)
                    acc[mi][ni] *= SPLIT_INV;
        }
#pragma unroll
        for (int h = 0; h < 4; ++h) {
            const int row = srow + h * 32;
            long ar = bm + row; if (ar > MDIM - 1) ar = MDIM - 1;
            GLOAD16(Ab + ar * DDIM + k0 + scol, &As[row][scol]);
            GLOAD16(Bb + (long)(bn + row) * DDIM + k0 + scol, &Bs[row][scol]);
        }
        __syncthreads();   // drains global_load_lds (vmcnt0) + makes LDS visible
#pragma unroll
        for (int kc = 0; kc < 2; ++kc) {
            f16x8 av[4], bv[4];
#pragma unroll
            for (int mi = 0; mi < 4; ++mi)
                av[mi] = *reinterpret_cast<const f16x8*>(&As[wr * 64 + mi * 16 + lr][kc * 32 + lk * 8]);
#pragma unroll
            for (int ni = 0; ni < 4; ++ni)
                bv[ni] = *reinterpret_cast<const f16x8*>(&Bs[wc * 64 + ni * 16 + lr][kc * 32 + lk * 8]);
#pragma unroll
            for (int mi = 0; mi < 4; ++mi)
#pragma unroll
                for (int ni = 0; ni < 4; ++ni)
                    acc[mi][ni] = __builtin_amdgcn_mfma_f32_16x16x32_f16(av[mi], bv[ni], acc[mi][ni], 0, 0, 0);
        }
        __syncthreads();   // all reads done before next stage overwrites
    }

#pragma unroll
    for (int ni = 0; ni < 4; ++ni) {
        const int col = bn + wc * 64 + ni * 16 + lr;
        const float bb = bias[col];
#pragma unroll
        for (int mi = 0; mi < 4; ++mi) {
            const long rbase = bm + wr * 64 + mi * 16 + lk * 4;
#pragma unroll
            for (int r = 0; r < 4; ++r) {
                const long row = rbase + r;
                if (row < MDIM) {
                    const float hv = fmaxf(acc[mi][ni][r] + bb, 0.f);
                    if (MODE == 0) {
                        const _Float16 h0 = (_Float16)hv;
                        H0[row * DDIM + col] = h0;
                        H1[row * DDIM + col] = (_Float16)((hv - (float)h0) * SPLIT_SCALE);
                    } else {
                        outF[row * DDIM + col] = hv;
                    }
                }
            }
        }
    }
}

// cls/at heads in fp32 (precision-critical for the top-k mask), N padded to 48.
__global__ __launch_bounds__(256)
void cls_gemm_f32(const float* __restrict__ H,
                  const float* __restrict__ Wc, const float* __restrict__ bc,
                  const float* __restrict__ Wa, const float* __restrict__ ba,
                  float* __restrict__ clsx, float* __restrict__ atout) {
    __shared__ float As[16][140];
    __shared__ float Bs[16][48];
    const int tid = threadIdx.x;
    const int tx = tid & 15, ty = tid >> 4;
    const long bm = (long)blockIdx.x * 128;

    float acc[8][3];
#pragma unroll
    for (int i = 0; i < 8; ++i)
#pragma unroll
        for (int j = 0; j < 3; ++j) acc[i][j] = 0.f;

    for (int k0 = 0; k0 < DDIM; k0 += 16) {
        __syncthreads();
#pragma unroll
        for (int h = 0; h < 2; ++h) {
            const int c = tid + h * 256;
            const int row = c >> 2;
            const int kc = (c & 3) << 2;
            long ar = bm + row; if (ar > MDIM - 1) ar = MDIM - 1;
            const float4 va = *reinterpret_cast<const float4*>(&H[ar * DDIM + k0 + kc]);
            As[kc + 0][row] = va.x; As[kc + 1][row] = va.y;
            As[kc + 2][row] = va.z; As[kc + 3][row] = va.w;
        }
        if (tid < 192) {
            const int n = tid >> 2;
            const int kc = (tid & 3) << 2;
            float4 w = make_float4(0.f, 0.f, 0.f, 0.f);
            if (n < 20)      w = *reinterpret_cast<const float4*>(&Wc[(long)n * DDIM + k0 + kc]);
            else if (n < 40) w = *reinterpret_cast<const float4*>(&Wa[(long)(n - 20) * DDIM + k0 + kc]);
            Bs[kc + 0][n] = w.x; Bs[kc + 1][n] = w.y;
            Bs[kc + 2][n] = w.z; Bs[kc + 3][n] = w.w;
        }
        __syncthreads();
#pragma unroll
        for (int kk = 0; kk < 16; ++kk) {
            float a[8];
            *(float4*)&a[0] = *(const float4*)&As[kk][ty * 8];
            *(float4*)&a[4] = *(const float4*)&As[kk][ty * 8 + 4];
            const float b0 = Bs[kk][tx];
            const float b1 = Bs[kk][tx + 16];
            const float b2 = Bs[kk][tx + 32];
#pragma unroll
            for (int i = 0; i < 8; ++i) {
                acc[i][0] = fmaf(a[i], b0, acc[i][0]);
                acc[i][1] = fmaf(a[i], b1, acc[i][1]);
                acc[i][2] = fmaf(a[i], b2, acc[i][2]);
            }
        }
    }

#pragma unroll
    for (int j = 0; j < 3; ++j) {
        const int col = tx + 16 * j;
        const bool isC = (col < 20);
        const bool isA = (col >= 20) && (col < 40);
        const float bvv = isC ? bc[col] : (isA ? ba[col - 20] : 0.f);
#pragma unroll
        for (int i = 0; i < 8; ++i) {
            const long row = bm + ty * 8 + i;
            if (row < MDIM) {
                const float v = acc[i][j] + bvv;
                if (isC)      clsx[row * CDIM + col] = v;
                else if (isA) atout[row * CDIM + col - 20] = v;
            }
        }
    }
}

// Per (stream,n,c): bitonic sort 750 values (pad to 1024 with +inf), emit rank KSEL.
__global__ __launch_bounds__(512)
void select_kth(const float* __restrict__ clsx_r, const float* __restrict__ clsx_f,
                float* __restrict__ kth) {
    __shared__ float s[1024];
    const int b = blockIdx.x;
    const int z = b / 640;
    const int rem = b - z * 640;
    const int n = rem / CDIM;
    const int c = rem - n * CDIM;
    const float* src = (z == 0) ? clsx_r : clsx_f;
    const int tid = threadIdx.x;

    for (int i = tid; i < 1024; i += 512)
        s[i] = (i < TDIM) ? src[((long)n * TDIM + i) * CDIM + c] : 3.402823466e38f;
    __syncthreads();

    for (int k = 2; k <= 1024; k <<= 1) {
        for (int j = k >> 1; j > 0; j >>= 1) {
            for (int i = tid; i < 1024; i += 512) {
                const int ixj = i ^ j;
                if (ixj > i) {
                    const bool up = ((i & k) == 0);
                    const float x = s[i], y = s[ixj];
                    if ((x > y) == up) { s[i] = y; s[ixj] = x; }
                }
            }
            __syncthreads();
        }
    }
    if (tid == 0) kth[b] = s[KSEL - 1];
}

__global__ __launch_bounds__(256)
void final_mask(float* __restrict__ out, const float* __restrict__ kth,
                const float* __restrict__ mul_r, const float* __restrict__ mul_f) {
    const int idx = blockIdx.x * 256 + threadIdx.x;
    if (idx >= NBATCH * TDIM * CDIM) return;
    const int m = idx / CDIM;
    const int c = idx - m * CDIM;
    const int n = m / TDIM;
    const float xr  = out[OFF_CLSX_R + idx];
    const float xf  = out[OFF_CLSX_F + idx];
    const float atr = out[OFF_CLSRA + idx];
    const float atf = out[OFF_CLSFA + idx];
    const float kr = kth[n * CDIM + c];
    const float kf = kth[640 + n * CDIM + c];
    out[OFF_CLSRA + idx] = (xr > kr) ? MASKV : atr;
    out[OFF_CLSFA + idx] = (xf > kf) ? MASKV : atf;
    out[OFF_TCAM + idx]  = (xr + OMEGAF * atr) * mul_r[c] + (xf + OMEGAF * atf) * mul_f[c];
}

extern "C" void kernel_launch(void* const* d_in, const int* in_sizes, int n_in,
                              void* d_out, int out_size, void* d_ws, size_t ws_size,
                              hipStream_t stream) {
    const float* inp    = (const float*)d_in[0];
    const float* Wfc_r  = (const float*)d_in[1];
    const float* bfc_r  = (const float*)d_in[2];
    const float* Wfc1_r = (const float*)d_in[3];
    const float* bfc1_r = (const float*)d_in[4];
    const float* Wfc_f  = (const float*)d_in[5];
    const float* bfc_f  = (const float*)d_in[6];
    const float* Wfc1_f = (const float*)d_in[7];
    const float* bfc1_f = (const float*)d_in[8];
    const float* Wcls_r = (const float*)d_in[9];
    const float* bcls_r = (const float*)d_in[10];
    const float* Wcls_f = (const float*)d_in[11];
    const float* bcls_f = (const float*)d_in[12];
    const float* Wra    = (const float*)d_in[13];
    const float* bra    = (const float*)d_in[14];
    const float* Wfa    = (const float*)d_in[15];
    const float* bfa    = (const float*)d_in[16];
    const float* mul_r  = (const float*)d_in[17];
    const float* mul_f  = (const float*)d_in[18];

    float* out = (float*)d_out;
    _Float16* wsA0 = (_Float16*)d_ws;           // 24000x1024 each
    _Float16* wsA1 = wsA0 + 24576000L;
    _Float16* wsH0 = wsA1 + 24576000L;
    _Float16* wsH1 = wsH0 + 24576000L;
    _Float16* wsW  = wsH1 + 24576000L;          // 8 x 1024x1024 f16
    float* kth = (float*)(wsW + 8L * 1048576L); // 1280 f32

    dim3 blk(256);
    dim3 gg(188, 8);

    // weight splits: [w*2] = hi, [w*2+1] = lo
    split_f16<<<dim3(512), blk, 0, stream>>>(Wfc_r,  1024, 1024, wsW + 0L * 1048576, wsW + 1L * 1048576);
    split_f16<<<dim3(512), blk, 0, stream>>>(Wfc1_r, 1024, 1024, wsW + 2L * 1048576, wsW + 3L * 1048576);
    split_f16<<<dim3(512), blk, 0, stream>>>(Wfc_f,  1024, 1024, wsW + 4L * 1048576, wsW + 5L * 1048576);
    split_f16<<<dim3(512), blk, 0, stream>>>(Wfc1_f, 1024, 1024, wsW + 6L * 1048576, wsW + 7L * 1048576);

    // ---- RGB stream ----
    split_f16<<<dim3(2048), blk, 0, stream>>>(inp, 2 * DDIM, MDIM, wsA0, wsA1);
    gemm_split_f16<0><<<gg, blk, 0, stream>>>(wsA0, wsA1, wsW + 0L * 1048576, wsW + 1L * 1048576,
                                              bfc_r, nullptr, wsH0, wsH1);
    gemm_split_f16<1><<<gg, blk, 0, stream>>>(wsH0, wsH1, wsW + 2L * 1048576, wsW + 3L * 1048576,
                                              bfc1_r, out + OFF_XR, nullptr, nullptr);
    cls_gemm_f32<<<dim3(188), blk, 0, stream>>>(out + OFF_XR, Wcls_r, bcls_r, Wra, bra,
                                                out + OFF_CLSX_R, out + OFF_CLSRA);

    // ---- Flow stream ----
    split_f16<<<dim3(2048), blk, 0, stream>>>(inp + DDIM, 2 * DDIM, MDIM, wsA0, wsA1);
    gemm_split_f16<0><<<gg, blk, 0, stream>>>(wsA0, wsA1, wsW + 4L * 1048576, wsW + 5L * 1048576,
                                              bfc_f, nullptr, wsH0, wsH1);
    gemm_split_f16<1><<<gg, blk, 0, stream>>>(wsH0, wsH1, wsW + 6L * 1048576, wsW + 7L * 1048576,
                                              bfc1_f, out + OFF_XF, nullptr, nullptr);
    cls_gemm_f32<<<dim3(188), blk, 0, stream>>>(out + OFF_XF, Wcls_f, bcls_f, Wfa, bfa,
                                                out + OFF_CLSX_F, out + OFF_CLSFA);

    select_kth<<<dim3(1280), dim3(512), 0, stream>>>(out + OFF_CLSX_R, out + OFF_CLSX_F, kth);
    final_mask<<<dim3((NBATCH * TDIM * CDIM + 255) / 256), blk, 0, stream>>>(out, kth, mul_r, mul_f);
}

// Round 4
// 1196.356 us; speedup vs baseline: 2.2094x; 1.0431x over previous
//
#include <hip/hip_runtime.h>
#include <cstdint>

typedef _Float16 f16x8 __attribute__((ext_vector_type(8)));
typedef float f32x4 __attribute__((ext_vector_type(4)));

#define MDIM 24000   // N*T rows
#define DDIM 1024
#define CDIM 20
#define TDIM 750
#define NBATCH 32
#define KSEL 657
#define MASKV -100.0f
#define OMEGAF 0.6f
#define SPLIT_SCALE 2048.0f
#define SPLIT_INV   4.8828125e-4f   // 2^-11 exact

// d_out element offsets (x_r, cls_x_r, cls_x_ra, x_f, cls_x_f, cls_x_fa, tcam)
#define OFF_XR     0L
#define OFF_CLSX_R 24576000L
#define OFF_CLSRA  25056000L
#define OFF_XF     25536000L
#define OFF_CLSX_F 50112000L
#define OFF_CLSFA  50592000L
#define OFF_TCAM   51072000L

#define GLOAD16(g, l) __builtin_amdgcn_global_load_lds( \
    (const __attribute__((address_space(1))) void*)(g), \
    (__attribute__((address_space(3))) void*)(l), 16, 0, 0)

// ---------------------------------------------------------------------------
// split helpers
// ---------------------------------------------------------------------------
__global__ __launch_bounds__(256)
void split_f16(const float* __restrict__ src, long srcStride, long nrows,
               _Float16* __restrict__ D0, _Float16* __restrict__ D1) {
    const long nvec = nrows * 128;
    for (long v = (long)blockIdx.x * 256 + threadIdx.x; v < nvec; v += (long)gridDim.x * 256) {
        const long row = v >> 7;
        const int c8 = (int)(v & 127) << 3;
        const float4 x0 = *reinterpret_cast<const float4*>(&src[row * srcStride + c8]);
        const float4 x1 = *reinterpret_cast<const float4*>(&src[row * srcStride + c8 + 4]);
        float xs[8] = {x0.x, x0.y, x0.z, x0.w, x1.x, x1.y, x1.z, x1.w};
        f16x8 h0, h1;
#pragma unroll
        for (int j = 0; j < 8; ++j) {
            const _Float16 a = (_Float16)xs[j];
            h0[j] = a;
            h1[j] = (_Float16)((xs[j] - (float)a) * SPLIT_SCALE);
        }
        *reinterpret_cast<f16x8*>(&D0[v << 3]) = h0;
        *reinterpret_cast<f16x8*>(&D1[v << 3]) = h1;
    }
}

// ---------------------------------------------------------------------------
// 256x256 8-phase split-f16 GEMM.  C = relu(A.W^T + bias), K' = 3x1024.
// 512 threads = 8 waves (2M x 4N); per-wave 128x64 out; BK=64.
// LDS: 2 buffers x (A 256x64 + B 256x64) f16 = 128 KiB, stored as 16x32
// subtiles (1024B): one global_load_lds issue = one subtile = one MFMA frag.
// ---------------------------------------------------------------------------
__device__ __forceinline__ void stage_ht(_Float16* sm, const _Float16* base,
                                         long rbase0, long rmax, int koff,
                                         int region, int h, int wv, int lane) {
    long r0 = rbase0 + (h * 8 + wv) * 16 + (lane >> 2);
    if (r0 > rmax) r0 = rmax;
    const _Float16* g = base + (r0 << 10) + koff + ((lane & 3) << 3);
    _Float16* d = &sm[region + (((h * 8 + wv) * 2) << 9) + lane * 8];
    GLOAD16(g, d);            // subtile cb=0
    GLOAD16(g + 32, d + 512); // subtile cb=1
}

template<int MODE>
__global__ __launch_bounds__(512, 2)
void gemm8_split_f16(const _Float16* __restrict__ gA0, const _Float16* __restrict__ gA1,
                     const _Float16* __restrict__ gB0, const _Float16* __restrict__ gB1,
                     const float* __restrict__ bias,
                     float* __restrict__ outF,
                     _Float16* __restrict__ H0, _Float16* __restrict__ H1) {
    __shared__ _Float16 sm[65536];   // 128 KiB

    const int tid = threadIdx.x;
    const int wv = tid >> 6;
    const int wr = wv >> 2;          // 0..1  (M)
    const int wc = wv & 3;           // 0..3  (N)
    const int lane = tid & 63;
    const int lr = lane & 15, lk = lane >> 4;
    const int wr8 = wr * 8, wc4 = wc * 4;

    // XCD-aware bijective swizzle: 376 = 8 * 47
    const int bid = blockIdx.x;
    const int wg = (bid & 7) * 47 + (bid >> 3);
    const long bm = (long)(wg >> 2) * 256;
    const int bn = (wg & 3) * 256;

    f32x4 acc[8][4];
#pragma unroll
    for (int f = 0; f < 8; ++f)
#pragma unroll
        for (int ni = 0; ni < 4; ++ni) acc[f][ni] = (f32x4){0.f, 0.f, 0.f, 0.f};

    f16x8 av[2][2], bv[4][2];

#define LDSA(b, rb, kk) (*(const f16x8*)&sm[((b)*2 + 0) * 16384 + ((((rb)*2) + (kk)) << 9) + lr * 32 + lk * 8])
#define LDSB(b, rb, kk) (*(const f16x8*)&sm[((b)*2 + 1) * 16384 + ((((rb)*2) + (kk)) << 9) + lr * 32 + lk * 8])

    // panel p = kt>>4: p0 -> (A0,B1), p1 -> (A1,B0), p2 -> (A0,B0)
#define STAGE(KT, X, H) do { const int _kt = (KT); if (_kt < 48) { \
    const int _p = _kt >> 4; \
    const _Float16* _b = (X) == 0 ? (_p == 1 ? gA1 : gA0) \
                                  : (_p == 0 ? gB1 : gB0); \
    stage_ht(sm, _b, (X) == 0 ? bm : (long)bn, (X) == 0 ? (long)(MDIM - 1) : 1023L, \
             (_kt & 15) << 6, ((_kt & 1) * 2 + (X)) * 16384, (H), wv, lane); } } while (0)

    // DOVM: 0 = none, 1 = vmcnt(4), 2 = vmcnt(0)
#define PHASE(BUF, PH, STKT, STX, STH, DOVM) do { \
    if ((PH) == 0) { \
        _Pragma("unroll") for (int ni = 0; ni < 4; ++ni) { \
            bv[ni][0] = LDSB(BUF, wc4 + ni, 0); \
            bv[ni][1] = LDSB(BUF, wc4 + ni, 1); } } \
    av[0][0] = LDSA(BUF, wr8 + (PH)*2 + 0, 0); av[0][1] = LDSA(BUF, wr8 + (PH)*2 + 0, 1); \
    av[1][0] = LDSA(BUF, wr8 + (PH)*2 + 1, 0); av[1][1] = LDSA(BUF, wr8 + (PH)*2 + 1, 1); \
    STAGE(STKT, STX, STH); \
    if ((DOVM) == 1) asm volatile("s_waitcnt vmcnt(4)" ::: "memory"); \
    if ((DOVM) == 2) asm volatile("s_waitcnt vmcnt(0)" ::: "memory"); \
    __builtin_amdgcn_s_barrier(); \
    asm volatile("s_waitcnt lgkmcnt(0)" ::: "memory"); \
    __builtin_amdgcn_sched_barrier(0); \
    __builtin_amdgcn_s_setprio(1); \
    _Pragma("unroll") for (int f = 0; f < 2; ++f) \
    _Pragma("unroll") for (int ni = 0; ni < 4; ++ni) \
    _Pragma("unroll") for (int kk = 0; kk < 2; ++kk) \
        acc[(PH)*2 + f][ni] = __builtin_amdgcn_mfma_f32_16x16x32_f16(av[f][kk], bv[ni][kk], acc[(PH)*2 + f][ni], 0, 0, 0); \
    __builtin_amdgcn_s_setprio(0); \
    __builtin_amdgcn_s_barrier(); \
} while (0)

    // prologue: tile0 fully, tile1's B; per-wave 12 loads, first 8 must land
    STAGE(0, 0, 0); STAGE(0, 0, 1); STAGE(0, 1, 0); STAGE(0, 1, 1);
    STAGE(1, 1, 0); STAGE(1, 1, 1);
    asm volatile("s_waitcnt vmcnt(4)" ::: "memory");
    __builtin_amdgcn_s_barrier();

    for (int it = 0; it < 23; ++it) {
        const int kt0 = it * 2;
        if (it == 16) {   // exact 2^-11 rescale after both lo panels (kt 0..31)
#pragma unroll
            for (int f = 0; f < 8; ++f)
#pragma unroll
                for (int ni = 0; ni < 4; ++ni) acc[f][ni] *= SPLIT_INV;
        }
        PHASE(0, 0, kt0 + 1, 0, 0, 0);
        PHASE(0, 1, kt0 + 1, 0, 1, 0);
        PHASE(0, 2, kt0 + 2, 1, 0, 0);
        PHASE(0, 3, kt0 + 2, 1, 1, 1);
        PHASE(1, 0, kt0 + 2, 0, 0, 0);
        PHASE(1, 1, kt0 + 2, 0, 1, 0);
        PHASE(1, 2, kt0 + 3, 1, 0, 0);
        PHASE(1, 3, kt0 + 3, 1, 1, 1);
    }
    // peeled last iter (tiles 46,47): MUST still stage tile 47's A panel
    // (round-3 bug: STKT=48 here left buf1-A holding tile 45 -> mask flips).
    PHASE(0, 0, 47, 0, 0, 0);   // stage A47 h0
    PHASE(0, 1, 47, 0, 1, 0);   // stage A47 h1
    PHASE(0, 2, 48, 1, 0, 0);
    PHASE(0, 3, 48, 1, 1, 2);   // drain A47+B47 (8 outstanding) before buf1 compute
    PHASE(1, 0, 48, 0, 0, 0);
    PHASE(1, 1, 48, 0, 1, 0);
    PHASE(1, 2, 48, 1, 0, 0);
    PHASE(1, 3, 48, 1, 1, 0);

    // epilogue: C/D layout col=lane&15, row=(lane>>4)*4+r (verified r2)
#pragma unroll
    for (int ni = 0; ni < 4; ++ni) {
        const int col = bn + wc * 64 + ni * 16 + lr;
        const float bb = bias[col];
#pragma unroll
        for (int f = 0; f < 8; ++f) {
            const long rbase = bm + wr * 128 + f * 16 + lk * 4;
#pragma unroll
            for (int r = 0; r < 4; ++r) {
                const long row = rbase + r;
                if (row < MDIM) {
                    const float hv = fmaxf(acc[f][ni][r] + bb, 0.f);
                    if (MODE == 0) {
                        const _Float16 h0 = (_Float16)hv;
                        H0[row * DDIM + col] = h0;
                        H1[row * DDIM + col] = (_Float16)((hv - (float)h0) * SPLIT_SCALE);
                    } else {
                        outF[row * DDIM + col] = hv;
                    }
                }
            }
        }
    }
#undef PHASE
#undef STAGE
#undef LDSA
#undef LDSB
}

// ---------------------------------------------------------------------------
// cls/at heads in fp32 (precision-critical for the top-k mask), N padded to 48.
// ---------------------------------------------------------------------------
__global__ __launch_bounds__(256)
void cls_gemm_f32(const float* __restrict__ H,
                  const float* __restrict__ Wc, const float* __restrict__ bc,
                  const float* __restrict__ Wa, const float* __restrict__ ba,
                  float* __restrict__ clsx, float* __restrict__ atout) {
    __shared__ float As[16][140];
    __shared__ float Bs[16][48];
    const int tid = threadIdx.x;
    const int tx = tid & 15, ty = tid >> 4;
    const long bm = (long)blockIdx.x * 128;

    float acc[8][3];
#pragma unroll
    for (int i = 0; i < 8; ++i)
#pragma unroll
        for (int j = 0; j < 3; ++j) acc[i][j] = 0.f;

    for (int k0 = 0; k0 < DDIM; k0 += 16) {
        __syncthreads();
#pragma unroll
        for (int h = 0; h < 2; ++h) {
            const int c = tid + h * 256;
            const int row = c >> 2;
            const int kc = (c & 3) << 2;
            long ar = bm + row; if (ar > MDIM - 1) ar = MDIM - 1;
            const float4 va = *reinterpret_cast<const float4*>(&H[ar * DDIM + k0 + kc]);
            As[kc + 0][row] = va.x; As[kc + 1][row] = va.y;
            As[kc + 2][row] = va.z; As[kc + 3][row] = va.w;
        }
        if (tid < 192) {
            const int n = tid >> 2;
            const int kc = (tid & 3) << 2;
            float4 w = make_float4(0.f, 0.f, 0.f, 0.f);
            if (n < 20)      w = *reinterpret_cast<const float4*>(&Wc[(long)n * DDIM + k0 + kc]);
            else if (n < 40) w = *reinterpret_cast<const float4*>(&Wa[(long)(n - 20) * DDIM + k0 + kc]);
            Bs[kc + 0][n] = w.x; Bs[kc + 1][n] = w.y;
            Bs[kc + 2][n] = w.z; Bs[kc + 3][n] = w.w;
        }
        __syncthreads();
#pragma unroll
        for (int kk = 0; kk < 16; ++kk) {
            float a[8];
            *(float4*)&a[0] = *(const float4*)&As[kk][ty * 8];
            *(float4*)&a[4] = *(const float4*)&As[kk][ty * 8 + 4];
            const float b0 = Bs[kk][tx];
            const float b1 = Bs[kk][tx + 16];
            const float b2 = Bs[kk][tx + 32];
#pragma unroll
            for (int i = 0; i < 8; ++i) {
                acc[i][0] = fmaf(a[i], b0, acc[i][0]);
                acc[i][1] = fmaf(a[i], b1, acc[i][1]);
                acc[i][2] = fmaf(a[i], b2, acc[i][2]);
            }
        }
    }

#pragma unroll
    for (int j = 0; j < 3; ++j) {
        const int col = tx + 16 * j;
        const bool isC = (col < 20);
        const bool isA = (col >= 20) && (col < 40);
        const float bvv = isC ? bc[col] : (isA ? ba[col - 20] : 0.f);
#pragma unroll
        for (int i = 0; i < 8; ++i) {
            const long row = bm + ty * 8 + i;
            if (row < MDIM) {
                const float v = acc[i][j] + bvv;
                if (isC)      clsx[row * CDIM + col] = v;
                else if (isA) atout[row * CDIM + col - 20] = v;
            }
        }
    }
}

// Per (stream,n,c): bitonic sort 750 values (pad to 1024 with +inf), emit rank KSEL.
__global__ __launch_bounds__(512)
void select_kth(const float* __restrict__ clsx_r, const float* __restrict__ clsx_f,
                float* __restrict__ kth) {
    __shared__ float s[1024];
    const int b = blockIdx.x;
    const int z = b / 640;
    const int rem = b - z * 640;
    const int n = rem / CDIM;
    const int c = rem - n * CDIM;
    const float* src = (z == 0) ? clsx_r : clsx_f;
    const int tid = threadIdx.x;

    for (int i = tid; i < 1024; i += 512)
        s[i] = (i < TDIM) ? src[((long)n * TDIM + i) * CDIM + c] : 3.402823466e38f;
    __syncthreads();

    for (int k = 2; k <= 1024; k <<= 1) {
        for (int j = k >> 1; j > 0; j >>= 1) {
            for (int i = tid; i < 1024; i += 512) {
                const int ixj = i ^ j;
                if (ixj > i) {
                    const bool up = ((i & k) == 0);
                    const float x = s[i], y = s[ixj];
                    if ((x > y) == up) { s[i] = y; s[ixj] = x; }
                }
            }
            __syncthreads();
        }
    }
    if (tid == 0) kth[b] = s[KSEL - 1];
}

__global__ __launch_bounds__(256)
void final_mask(float* __restrict__ out, const float* __restrict__ kth,
                const float* __restrict__ mul_r, const float* __restrict__ mul_f) {
    const int idx = blockIdx.x * 256 + threadIdx.x;
    if (idx >= NBATCH * TDIM * CDIM) return;
    const int m = idx / CDIM;
    const int c = idx - m * CDIM;
    const int n = m / TDIM;
    const float xr  = out[OFF_CLSX_R + idx];
    const float xf  = out[OFF_CLSX_F + idx];
    const float atr = out[OFF_CLSRA + idx];
    const float atf = out[OFF_CLSFA + idx];
    const float kr = kth[n * CDIM + c];
    const float kf = kth[640 + n * CDIM + c];
    out[OFF_CLSRA + idx] = (xr > kr) ? MASKV : atr;
    out[OFF_CLSFA + idx] = (xf > kf) ? MASKV : atf;
    out[OFF_TCAM + idx]  = (xr + OMEGAF * atr) * mul_r[c] + (xf + OMEGAF * atf) * mul_f[c];
}

extern "C" void kernel_launch(void* const* d_in, const int* in_sizes, int n_in,
                              void* d_out, int out_size, void* d_ws, size_t ws_size,
                              hipStream_t stream) {
    const float* inp    = (const float*)d_in[0];
    const float* Wfc_r  = (const float*)d_in[1];
    const float* bfc_r  = (const float*)d_in[2];
    const float* Wfc1_r = (const float*)d_in[3];
    const float* bfc1_r = (const float*)d_in[4];
    const float* Wfc_f  = (const float*)d_in[5];
    const float* bfc_f  = (const float*)d_in[6];
    const float* Wfc1_f = (const float*)d_in[7];
    const float* bfc1_f = (const float*)d_in[8];
    const float* Wcls_r = (const float*)d_in[9];
    const float* bcls_r = (const float*)d_in[10];
    const float* Wcls_f = (const float*)d_in[11];
    const float* bcls_f = (const float*)d_in[12];
    const float* Wra    = (const float*)d_in[13];
    const float* bra    = (const float*)d_in[14];
    const float* Wfa    = (const float*)d_in[15];
    const float* bfa    = (const float*)d_in[16];
    const float* mul_r  = (const float*)d_in[17];
    const float* mul_f  = (const float*)d_in[18];

    float* out = (float*)d_out;
    _Float16* wsA0 = (_Float16*)d_ws;           // 24000x1024 each
    _Float16* wsA1 = wsA0 + 24576000L;
    _Float16* wsH0 = wsA1 + 24576000L;
    _Float16* wsH1 = wsH0 + 24576000L;
    _Float16* wsW  = wsH1 + 24576000L;          // 8 x 1024x1024 f16
    float* kth = (float*)(wsW + 8L * 1048576L); // 1280 f32

    dim3 blk(256);
    dim3 gg(376);       // 94 M-blocks x 4 N-blocks
    dim3 bb(512);

    split_f16<<<dim3(512), blk, 0, stream>>>(Wfc_r,  1024, 1024, wsW + 0L * 1048576, wsW + 1L * 1048576);
    split_f16<<<dim3(512), blk, 0, stream>>>(Wfc1_r, 1024, 1024, wsW + 2L * 1048576, wsW + 3L * 1048576);
    split_f16<<<dim3(512), blk, 0, stream>>>(Wfc_f,  1024, 1024, wsW + 4L * 1048576, wsW + 5L * 1048576);
    split_f16<<<dim3(512), blk, 0, stream>>>(Wfc1_f, 1024, 1024, wsW + 6L * 1048576, wsW + 7L * 1048576);

    // ---- RGB stream ----
    split_f16<<<dim3(2048), blk, 0, stream>>>(inp, 2 * DDIM, MDIM, wsA0, wsA1);
    gemm8_split_f16<0><<<gg, bb, 0, stream>>>(wsA0, wsA1, wsW + 0L * 1048576, wsW + 1L * 1048576,
                                              bfc_r, nullptr, wsH0, wsH1);
    gemm8_split_f16<1><<<gg, bb, 0, stream>>>(wsH0, wsH1, wsW + 2L * 1048576, wsW + 3L * 1048576,
                                              bfc1_r, out + OFF_XR, nullptr, nullptr);
    cls_gemm_f32<<<dim3(188), blk, 0, stream>>>(out + OFF_XR, Wcls_r, bcls_r, Wra, bra,
                                                out + OFF_CLSX_R, out + OFF_CLSRA);

    // ---- Flow stream ----
    split_f16<<<dim3(2048), blk, 0, stream>>>(inp + DDIM, 2 * DDIM, MDIM, wsA0, wsA1);
    gemm8_split_f16<0><<<gg, bb, 0, stream>>>(wsA0, wsA1, wsW + 4L * 1048576, wsW + 5L * 1048576,
                                              bfc_f, nullptr, wsH0, wsH1);
    gemm8_split_f16<1><<<gg, bb, 0, stream>>>(wsH0, wsH1, wsW + 6L * 1048576, wsW + 7L * 1048576,
                                              bfc1_f, out + OFF_XF, nullptr, nullptr);
    cls_gemm_f32<<<dim3(188), blk, 0, stream>>>(out + OFF_XF, Wcls_f, bcls_f, Wfa, bfa,
                                                out + OFF_CLSX_F, out + OFF_CLSFA);

    select_kth<<<dim3(1280), dim3(512), 0, stream>>>(out + OFF_CLSX_R, out + OFF_CLSX_F, kth);
    final_mask<<<dim3((NBATCH * TDIM * CDIM + 255) / 256), blk, 0, stream>>>(out, kth, mul_r, mul_f);
}